// Round 13
// baseline (429.828 us; speedup 1.0000x reference)
//
#include <hip/hip_runtime.h>

#define B_ 2
#define N_ 1024
#define C_ 1024
#define H_ 16
#define HD_ 64
#define PKU 40  // ushort stride per LDS row (80B): 16B-aligned b128, 2-way banks

typedef short short8 __attribute__((ext_vector_type(8)));
typedef float f32x4 __attribute__((ext_vector_type(4)));
typedef unsigned short ushort_t;

// ---------- wave-wide (64-lane) helpers ----------
__device__ __forceinline__ float wsumf(float x) {
#pragma unroll
  for (int off = 32; off; off >>= 1) x += __shfl_xor(x, off, 64);
  return x;
}
__device__ __forceinline__ unsigned orderu(float f) {
  unsigned b = __float_as_uint(f);
  return (b & 0x80000000u) ? ~b : (b | 0x80000000u);
}
__device__ __forceinline__ float iorderu(unsigned x) {
  unsigned b = (x & 0x80000000u) ? (x & 0x7FFFFFFFu) : ~x;
  return __uint_as_float(b);
}

// 2-term split f32 -> packed u32: hi bf16 low16, lo bf16 high16 (RTNE)
__device__ __forceinline__ unsigned splitf2(float f) {
  unsigned u = __float_as_uint(f);
  unsigned t = (u + 0x7fffu + ((u >> 16) & 1u)) & 0xffff0000u;
  float r = f - __uint_as_float(t);  // exact
  unsigned v = __float_as_uint(r);
  unsigned tv = v + 0x7fffu + ((v >> 16) & 1u);
  return (t >> 16) | (tv & 0xffff0000u);
}
// 3-term split: hm = hi|mid packed u32, lo = third bf16 term
// (h ≡ splitf2's h; m ≡ splitf2's lo — identical rounding)
__device__ __forceinline__ void splitf3(float f, unsigned& hm, ushort_t& lo) {
  unsigned u = __float_as_uint(f);
  unsigned t = (u + 0x7fffu + ((u >> 16) & 1u)) & 0xffff0000u;
  float r1 = f - __uint_as_float(t);  // exact
  unsigned v = __float_as_uint(r1);
  unsigned tv = (v + 0x7fffu + ((v >> 16) & 1u)) & 0xffff0000u;
  float r2 = r1 - __uint_as_float(tv);  // exact
  unsigned w = __float_as_uint(r2);
  unsigned tw = w + 0x7fffu + ((w >> 16) & 1u);
  hm = (t >> 16) | tv;
  lo = (ushort_t)(tw >> 16);
}

// ---------- NKAT per-token factor ----------
__global__ __launch_bounds__(64) void factor_kernel(
    const float* __restrict__ x, const float* __restrict__ alpha_p,
    const float* __restrict__ beta_p, float* __restrict__ fac) {
  const int row = blockIdx.x;
  const int lane = threadIdx.x;
  const float4* xr = (const float4*)(x + (size_t)row * C_);
  float s = 0.f, ss = 0.f;
#pragma unroll
  for (int j = 0; j < 4; ++j) {
    float4 v = xr[lane + 64 * j];
    s += v.x + v.y + v.z + v.w;
    ss += v.x * v.x + v.y * v.y + v.z * v.z + v.w * v.w;
  }
  s = wsumf(s);
  ss = wsumf(ss);
  const float mean = s * (1.f / 1024.f);
  const float var = ss * (1.f / 1024.f) - mean * mean;
  const float theta =
      alpha_p[0] * tanhf(mean) + beta_p[0] * (1.f / (1.f + __expf(-var)));
  if (lane == 0) fac[row] = 1.f + 0.45125f * theta;  // lc = 0.5*0.95^2
}

// ---------- elementwise 3-term split into planes ----------
__global__ __launch_bounds__(256) void split3_kernel(
    const float* __restrict__ src, ushort_t* __restrict__ ph,
    ushort_t* __restrict__ pm, ushort_t* __restrict__ pl) {
  const int i = (blockIdx.x * 256 + threadIdx.x) * 4;
  const float4 v = *(const float4*)(src + i);
  unsigned h0, h1, h2, h3;
  ushort_t l0, l1, l2, l3;
  splitf3(v.x, h0, l0);
  splitf3(v.y, h1, l1);
  splitf3(v.z, h2, l2);
  splitf3(v.w, h3, l3);
  *(ushort4*)(ph + i) =
      make_ushort4(h0 & 0xffffu, h1 & 0xffffu, h2 & 0xffffu, h3 & 0xffffu);
  *(ushort4*)(pm + i) = make_ushort4(h0 >> 16, h1 >> 16, h2 >> 16, h3 >> 16);
  *(ushort4*)(pl + i) = make_ushort4(l0, l1, l2, l3);
}

// ---------- elementwise 2-term split into planes ----------
__global__ __launch_bounds__(256) void split2_kernel(
    const float* __restrict__ src, ushort_t* __restrict__ ph,
    ushort_t* __restrict__ pm) {
  const int i = (blockIdx.x * 256 + threadIdx.x) * 4;
  const float4 v = *(const float4*)(src + i);
  const unsigned p0 = splitf2(v.x), p1 = splitf2(v.y), p2 = splitf2(v.z),
                 p3 = splitf2(v.w);
  *(ushort4*)(ph + i) =
      make_ushort4(p0 & 0xffffu, p1 & 0xffffu, p2 & 0xffffu, p3 & 0xffffu);
  *(ushort4*)(pm + i) = make_ushort4(p0 >> 16, p1 >> 16, p2 >> 16, p3 >> 16);
}

// ---------- qk GEMM: 3-plane inputs, 6 products, 128x64 tile, BK=32 ----------
__global__ __launch_bounds__(256) void gemm_qk_kernel(
    const ushort_t* __restrict__ xh, const ushort_t* __restrict__ xm,
    const ushort_t* __restrict__ xl, const ushort_t* __restrict__ wh,
    const ushort_t* __restrict__ wm, const ushort_t* __restrict__ wl,
    float* __restrict__ q, float* __restrict__ ktb) {
  __shared__ ushort_t Ah[128 * PKU], Am[128 * PKU], Al[128 * PKU];
  __shared__ ushort_t Bh[64 * PKU], Bm[64 * PKU], Bl[64 * PKU];
  f32x4 acc[4][2];
#pragma unroll
  for (int i = 0; i < 4; ++i)
#pragma unroll
    for (int j = 0; j < 2; ++j) acc[i][j] = (f32x4){0.f, 0.f, 0.f, 0.f};
  const int tid = threadIdx.x;
  const int lane = tid & 63;
  const int m0 = blockIdx.y * 128, n0 = blockIdx.x * 64;
  const int wro = ((tid >> 7) & 1) * 64;
  const int wco = ((tid >> 6) & 1) * 32;
  const int a_m = tid >> 3, a_k4 = (tid & 7) * 4;
  const int b_k = tid >> 4, b_j4 = (tid & 15) * 4;
  const int fr = lane & 15, fk = (lane >> 4) * 8;

  ushort4 aR[3][4], bR[3][2];
  const ushort_t* ap[3] = {xh, xm, xl};
  const ushort_t* bp[3] = {wh, wm, wl};
#pragma unroll
  for (int p = 0; p < 3; ++p) {
#pragma unroll
    for (int j = 0; j < 4; ++j)
      aR[p][j] =
          *(const ushort4*)(ap[p] + (size_t)(m0 + a_m + 32 * j) * 1024 + a_k4);
#pragma unroll
    for (int h2 = 0; h2 < 2; ++h2)
      bR[p][h2] =
          *(const ushort4*)(bp[p] + (size_t)(b_k + 16 * h2) * 3072 + n0 + b_j4);
  }

  for (int kt = 0; kt < 32; ++kt) {
    __syncthreads();  // prior iteration's frag reads done
#pragma unroll
    for (int j = 0; j < 4; ++j) {
      *(ushort4*)&Ah[(a_m + 32 * j) * PKU + a_k4] = aR[0][j];
      *(ushort4*)&Am[(a_m + 32 * j) * PKU + a_k4] = aR[1][j];
      *(ushort4*)&Al[(a_m + 32 * j) * PKU + a_k4] = aR[2][j];
    }
#pragma unroll
    for (int h2 = 0; h2 < 2; ++h2) {
      const int kk = b_k + 16 * h2;
      Bh[(b_j4 + 0) * PKU + kk] = bR[0][h2].x;
      Bh[(b_j4 + 1) * PKU + kk] = bR[0][h2].y;
      Bh[(b_j4 + 2) * PKU + kk] = bR[0][h2].z;
      Bh[(b_j4 + 3) * PKU + kk] = bR[0][h2].w;
      Bm[(b_j4 + 0) * PKU + kk] = bR[1][h2].x;
      Bm[(b_j4 + 1) * PKU + kk] = bR[1][h2].y;
      Bm[(b_j4 + 2) * PKU + kk] = bR[1][h2].z;
      Bm[(b_j4 + 3) * PKU + kk] = bR[1][h2].w;
      Bl[(b_j4 + 0) * PKU + kk] = bR[2][h2].x;
      Bl[(b_j4 + 1) * PKU + kk] = bR[2][h2].y;
      Bl[(b_j4 + 2) * PKU + kk] = bR[2][h2].z;
      Bl[(b_j4 + 3) * PKU + kk] = bR[2][h2].w;
    }
    __syncthreads();
    if (kt + 1 < 32) {  // prefetch next k-tile; hides under MFMA
      const int kb = (kt + 1) * 32;
#pragma unroll
      for (int p = 0; p < 3; ++p) {
#pragma unroll
        for (int j = 0; j < 4; ++j)
          aR[p][j] = *(const ushort4*)(ap[p] +
                                       (size_t)(m0 + a_m + 32 * j) * 1024 + kb +
                                       a_k4);
#pragma unroll
        for (int h2 = 0; h2 < 2; ++h2)
          bR[p][h2] = *(const ushort4*)(bp[p] +
                                        (size_t)(kb + b_k + 16 * h2) * 3072 +
                                        n0 + b_j4);
      }
    }
    short8 fah[4], fam[4], fal[4];
#pragma unroll
    for (int rt = 0; rt < 4; ++rt) {
      const int ba = (wro + rt * 16 + fr) * PKU + fk;
      fah[rt] = *(const short8*)&Ah[ba];
      fam[rt] = *(const short8*)&Am[ba];
      fal[rt] = *(const short8*)&Al[ba];
    }
#pragma unroll
    for (int ct = 0; ct < 2; ++ct) {
      const int bb = (wco + ct * 16 + fr) * PKU + fk;
      const short8 fbh = *(const short8*)&Bh[bb];
      const short8 fbm = *(const short8*)&Bm[bb];
      const short8 fbl = *(const short8*)&Bl[bb];
#pragma unroll
      for (int rt = 0; rt < 4; ++rt) {
        f32x4 c = acc[rt][ct];
        c = __builtin_amdgcn_mfma_f32_16x16x32_bf16(fah[rt], fbl, c, 0, 0, 0);
        c = __builtin_amdgcn_mfma_f32_16x16x32_bf16(fal[rt], fbh, c, 0, 0, 0);
        c = __builtin_amdgcn_mfma_f32_16x16x32_bf16(fam[rt], fbm, c, 0, 0, 0);
        c = __builtin_amdgcn_mfma_f32_16x16x32_bf16(fah[rt], fbm, c, 0, 0, 0);
        c = __builtin_amdgcn_mfma_f32_16x16x32_bf16(fam[rt], fbh, c, 0, 0, 0);
        c = __builtin_amdgcn_mfma_f32_16x16x32_bf16(fah[rt], fbh, c, 0, 0, 0);
        acc[rt][ct] = c;
      }
    }
  }

  const int rbase = (lane >> 4) * 4, cc = lane & 15;
#pragma unroll
  for (int rt = 0; rt < 4; ++rt) {
    const int m = m0 + wro + rt * 16 + rbase;
    const int bb2 = m >> 10, nn = m & 1023;
#pragma unroll
    for (int ct = 0; ct < 2; ++ct) {
      const int j = n0 + wco + ct * 16 + cc;
      const int sel = j >> 10, hh = (j >> 6) & 15, d0 = j & 63;
      const f32x4 c = acc[rt][ct];
      if (sel == 1) {  // K transposed: contiguous along token index nn
        *(float4*)(ktb + (((size_t)(bb2 * 16 + hh) * HD_ + d0) << 10) + nn) =
            make_float4(c[0], c[1], c[2], c[3]);
      } else {
        float* dst = q + (((size_t)(bb2 * 16 + hh) << 10) + nn) * HD_ + d0;
        dst[0] = c[0];
        dst[HD_] = c[1];
        dst[2 * HD_] = c[2];
        dst[3 * HD_] = c[3];
      }
    }
  }
}

// ---------- 2-plane (3-product) MFMA core, 128x64 tile ----------
__device__ __forceinline__ void mfma_core2p(
    const ushort_t* __restrict__ Aph, const ushort_t* __restrict__ Apm,
    const ushort_t* __restrict__ Bph, const ushort_t* __restrict__ Bpm,
    int ldb, int m0, int n0, ushort_t* Ah, ushort_t* Am, ushort_t* Bh,
    ushort_t* Bm, f32x4 acc[4][2]) {
  const int tid = threadIdx.x;
  const int lane = tid & 63;
  const int wro = ((tid >> 7) & 1) * 64;
  const int wco = ((tid >> 6) & 1) * 32;
  const int a_m = tid >> 3, a_k4 = (tid & 7) * 4;
  const int b_k = tid >> 4, b_j4 = (tid & 15) * 4;
  const int fr = lane & 15, fk = (lane >> 4) * 8;

  ushort4 aR[2][4], bR[2][2];
  const ushort_t* ap[2] = {Aph, Apm};
  const ushort_t* bp[2] = {Bph, Bpm};
#pragma unroll
  for (int p = 0; p < 2; ++p) {
#pragma unroll
    for (int j = 0; j < 4; ++j)
      aR[p][j] =
          *(const ushort4*)(ap[p] + (size_t)(m0 + a_m + 32 * j) * 1024 + a_k4);
#pragma unroll
    for (int h2 = 0; h2 < 2; ++h2)
      bR[p][h2] =
          *(const ushort4*)(bp[p] + (size_t)(b_k + 16 * h2) * ldb + n0 + b_j4);
  }

  for (int kt = 0; kt < 32; ++kt) {
    __syncthreads();
#pragma unroll
    for (int j = 0; j < 4; ++j) {
      *(ushort4*)&Ah[(a_m + 32 * j) * PKU + a_k4] = aR[0][j];
      *(ushort4*)&Am[(a_m + 32 * j) * PKU + a_k4] = aR[1][j];
    }
#pragma unroll
    for (int h2 = 0; h2 < 2; ++h2) {
      const int kk = b_k + 16 * h2;
      Bh[(b_j4 + 0) * PKU + kk] = bR[0][h2].x;
      Bh[(b_j4 + 1) * PKU + kk] = bR[0][h2].y;
      Bh[(b_j4 + 2) * PKU + kk] = bR[0][h2].z;
      Bh[(b_j4 + 3) * PKU + kk] = bR[0][h2].w;
      Bm[(b_j4 + 0) * PKU + kk] = bR[1][h2].x;
      Bm[(b_j4 + 1) * PKU + kk] = bR[1][h2].y;
      Bm[(b_j4 + 2) * PKU + kk] = bR[1][h2].z;
      Bm[(b_j4 + 3) * PKU + kk] = bR[1][h2].w;
    }
    __syncthreads();
    if (kt + 1 < 32) {
      const int kb = (kt + 1) * 32;
#pragma unroll
      for (int p = 0; p < 2; ++p) {
#pragma unroll
        for (int j = 0; j < 4; ++j)
          aR[p][j] = *(const ushort4*)(ap[p] +
                                       (size_t)(m0 + a_m + 32 * j) * 1024 + kb +
                                       a_k4);
#pragma unroll
        for (int h2 = 0; h2 < 2; ++h2)
          bR[p][h2] = *(const ushort4*)(bp[p] +
                                        (size_t)(kb + b_k + 16 * h2) * ldb +
                                        n0 + b_j4);
      }
    }
    short8 fah[4], fam[4];
#pragma unroll
    for (int rt = 0; rt < 4; ++rt) {
      const int ba = (wro + rt * 16 + fr) * PKU + fk;
      fah[rt] = *(const short8*)&Ah[ba];
      fam[rt] = *(const short8*)&Am[ba];
    }
#pragma unroll
    for (int ct = 0; ct < 2; ++ct) {
      const int bb = (wco + ct * 16 + fr) * PKU + fk;
      const short8 fbh = *(const short8*)&Bh[bb];
      const short8 fbm = *(const short8*)&Bm[bb];
#pragma unroll
      for (int rt = 0; rt < 4; ++rt) {
        f32x4 c = acc[rt][ct];
        c = __builtin_amdgcn_mfma_f32_16x16x32_bf16(fah[rt], fbm, c, 0, 0, 0);
        c = __builtin_amdgcn_mfma_f32_16x16x32_bf16(fam[rt], fbh, c, 0, 0, 0);
        c = __builtin_amdgcn_mfma_f32_16x16x32_bf16(fah[rt], fbh, c, 0, 0, 0);
        acc[rt][ct] = c;
      }
    }
  }
}

// ---------- v: w_qkv cols 2048..3071 -> v (B,H,N,HD) ----------
__global__ __launch_bounds__(256) void gemm_v_kernel(
    const ushort_t* __restrict__ xh, const ushort_t* __restrict__ xm,
    const ushort_t* __restrict__ wh, const ushort_t* __restrict__ wm,
    float* __restrict__ v) {
  __shared__ ushort_t Ah[128 * PKU], Am[128 * PKU];
  __shared__ ushort_t Bh[64 * PKU], Bm[64 * PKU];
  f32x4 acc[4][2];
#pragma unroll
  for (int i = 0; i < 4; ++i)
#pragma unroll
    for (int j = 0; j < 2; ++j) acc[i][j] = (f32x4){0.f, 0.f, 0.f, 0.f};
  const int m0 = blockIdx.y * 128, n0 = 2048 + blockIdx.x * 64;
  mfma_core2p(xh, xm, wh, wm, 3072, m0, n0, Ah, Am, Bh, Bm, acc);

  const int lane = threadIdx.x & 63;
  const int wro = ((threadIdx.x >> 7) & 1) * 64;
  const int wco = ((threadIdx.x >> 6) & 1) * 32;
  const int rbase = (lane >> 4) * 4, cc = lane & 15;
#pragma unroll
  for (int rt = 0; rt < 4; ++rt) {
    const int m = m0 + wro + rt * 16 + rbase;
    const int bb = m >> 10, nn = m & 1023;
#pragma unroll
    for (int ct = 0; ct < 2; ++ct) {
      const int jv = (n0 - 2048) + wco + ct * 16 + cc;
      const int hh = (jv >> 6) & 15, d0 = jv & 63;
      const f32x4 c = acc[rt][ct];
      float* dst = v + (((size_t)(bb * 16 + hh) << 10) + nn) * HD_ + d0;
      dst[0] = c[0];
      dst[HD_] = c[1];
      dst[2 * HD_] = c[2];
      dst[3 * HD_] = c[3];
    }
  }
}

// ---------- out = attn_out @ w_out + b_out (plane inputs) ----------
__global__ __launch_bounds__(256) void gemm_out_kernel(
    const ushort_t* __restrict__ aoh, const ushort_t* __restrict__ aom,
    const ushort_t* __restrict__ wh, const ushort_t* __restrict__ wm,
    const float* __restrict__ bias, float* __restrict__ out) {
  __shared__ ushort_t Ah[128 * PKU], Am[128 * PKU];
  __shared__ ushort_t Bh[64 * PKU], Bm[64 * PKU];
  f32x4 acc[4][2];
#pragma unroll
  for (int i = 0; i < 4; ++i)
#pragma unroll
    for (int j = 0; j < 2; ++j) acc[i][j] = (f32x4){0.f, 0.f, 0.f, 0.f};
  const int m0 = blockIdx.y * 128, n0 = blockIdx.x * 64;
  mfma_core2p(aoh, aom, wh, wm, 1024, m0, n0, Ah, Am, Bh, Bm, acc);

  const int lane = threadIdx.x & 63;
  const int wro = ((threadIdx.x >> 7) & 1) * 64;
  const int wco = ((threadIdx.x >> 6) & 1) * 32;
  const int rbase = (lane >> 4) * 4, cc = lane & 15;
#pragma unroll
  for (int rt = 0; rt < 4; ++rt) {
    const int m = m0 + wro + rt * 16 + rbase;
#pragma unroll
    for (int ct = 0; ct < 2; ++ct) {
      const int j = n0 + wco + ct * 16 + cc;
      const float bj = bias[j];
      const f32x4 c = acc[rt][ct];
      float* dst = out + (size_t)m * C_ + j;
      dst[0] = c[0] + bj;
      dst[C_] = c[1] + bj;
      dst[2 * C_] = c[2] + bj;
      dst[3 * C_] = c[3] + bj;
    }
  }
}

// ---------- attention: round-12 kernel; output written as 2 bf16 planes ----------
__global__ __launch_bounds__(256) void attn_kernel(
    const float* __restrict__ qw, const float* __restrict__ kt,
    const float* __restrict__ vw, const float* __restrict__ fac,
    ushort_t* __restrict__ aoh, ushort_t* __restrict__ aom) {
  const int lane = threadIdx.x & 63;
  const int wid = threadIdx.x >> 6;
  const int qblk = blockIdx.x * 16;
  const int bh = qblk >> 10;
  const int b = bh >> 4, h = bh & 15;
  const int q0 = (qblk & (N_ - 1)) + wid * 4;

  __shared__ __align__(16) float q_ldsT[4][HD_][4];
  __shared__ unsigned su[4][64];
  __shared__ float sv[4][64];
  __shared__ int ck[4][64];
  __shared__ float cv[4][64];

  {
    const int qq = lane >> 4, dp = (lane & 15) << 2;
    const float4 v =
        *(const float4*)(qw + ((size_t)bh * N_ + q0 + qq) * HD_ + dp);
    q_ldsT[wid][dp + 0][qq] = v.x;
    q_ldsT[wid][dp + 1][qq] = v.y;
    q_ldsT[wid][dp + 2][qq] = v.z;
    q_ldsT[wid][dp + 3][qq] = v.w;
  }

  const float* ktb = kt + ((size_t)bh * HD_ * N_);
  const unsigned long long ltmask = (1ull << lane) - 1ull;
  unsigned u[4][16];

  for (int pass = 0; pass < 4; ++pass) {
    float acc[4][4];
#pragma unroll
    for (int a = 0; a < 4; ++a)
#pragma unroll
      for (int c = 0; c < 4; ++c) acc[a][c] = 0.f;
    const float* kp = ktb + (pass << 8) + (lane << 2);
#pragma unroll 4
    for (int d = 0; d < HD_; ++d) {
      const float4 kv = *(const float4*)(kp + (size_t)d * N_);
      const float4 qv = *(const float4*)(&q_ldsT[wid][d][0]);
      acc[0][0] = fmaf(kv.x, qv.x, acc[0][0]);
      acc[0][1] = fmaf(kv.x, qv.y, acc[0][1]);
      acc[0][2] = fmaf(kv.x, qv.z, acc[0][2]);
      acc[0][3] = fmaf(kv.x, qv.w, acc[0][3]);
      acc[1][0] = fmaf(kv.y, qv.x, acc[1][0]);
      acc[1][1] = fmaf(kv.y, qv.y, acc[1][1]);
      acc[1][2] = fmaf(kv.y, qv.z, acc[1][2]);
      acc[1][3] = fmaf(kv.y, qv.w, acc[1][3]);
      acc[2][0] = fmaf(kv.z, qv.x, acc[2][0]);
      acc[2][1] = fmaf(kv.z, qv.y, acc[2][1]);
      acc[2][2] = fmaf(kv.z, qv.z, acc[2][2]);
      acc[2][3] = fmaf(kv.z, qv.w, acc[2][3]);
      acc[3][0] = fmaf(kv.w, qv.x, acc[3][0]);
      acc[3][1] = fmaf(kv.w, qv.y, acc[3][1]);
      acc[3][2] = fmaf(kv.w, qv.z, acc[3][2]);
      acc[3][3] = fmaf(kv.w, qv.w, acc[3][3]);
    }
#pragma unroll
    for (int jl = 0; jl < 4; ++jl)
#pragma unroll
      for (int q = 0; q < 4; ++q)
        u[q][(pass << 2) + jl] = orderu((acc[jl][q] * 0.125f) / 0.8f);
  }

  unsigned mu[4], l0[4];
#pragma unroll
  for (int q = 0; q < 4; ++q) {
    unsigned mq = u[q][0];
#pragma unroll
    for (int j = 1; j < 16; ++j) mq = max(mq, u[q][j]);
    mu[q] = mq;
    l0[q] = mq;
  }
#pragma unroll
  for (int off = 32; off; off >>= 1) {
#pragma unroll
    for (int q = 0; q < 4; ++q) {
      mu[q] = max(mu[q], (unsigned)__shfl_xor((int)mu[q], off, 64));
      l0[q] = min(l0[q], (unsigned)__shfl_xor((int)l0[q], off, 64));
    }
  }

  unsigned lo[4], hi[4];
#pragma unroll
  for (int q = 0; q < 4; ++q) {
    lo[q] = l0[q];
    hi[q] = mu[q];
  }
  while ((lo[0] < hi[0]) | (lo[1] < hi[1]) | (lo[2] < hi[2]) |
         (lo[3] < hi[3])) {
#pragma unroll
    for (int q = 0; q < 4; ++q) {
      if (lo[q] < hi[q]) {
        const unsigned mid = lo[q] + ((hi[q] - lo[q]) >> 1) + 1u;
        int c = 0;
#pragma unroll
        for (int j = 0; j < 16; ++j)
          c += (int)__popcll(__ballot(u[q][j] >= mid));
        if (c >= 64) lo[q] = mid;
        else hi[q] = mid - 1u;
      }
    }
  }

  const float* vb = vw + ((size_t)bh << 16);
#pragma unroll
  for (int qq = 0; qq < 4; ++qq) {
    const unsigned kthu = lo[qq];
    const float m = iorderu(mu[qq]);

    float e[16];
    float zl = 0.f;
#pragma unroll
    for (int j = 0; j < 16; ++j) {
      const float ej = (u[qq][j] >= kthu) ? __expf(iorderu(u[qq][j]) - m) : 0.f;
      e[j] = ej;
      zl += ej;
    }
    const float Z = wsumf(zl);
    const float limit = 0.9f * Z;

    int base = 0;
#pragma unroll
    for (int j = 0; j < 16; ++j) {
      const bool f = (u[qq][j] >= kthu);
      const unsigned long long mb = __ballot(f);
      if (f) {
        const int pos = base + (int)__popcll(mb & ltmask);
        if (pos < 64) {
          su[wid][pos] = u[qq][j];
          sv[wid][pos] = e[j];
        }
      }
      base += (int)__popcll(mb);
    }

    unsigned sk = ~su[wid][lane];
    float se = sv[wid][lane];
#pragma unroll
    for (int k = 2; k <= 64; k <<= 1) {
#pragma unroll
      for (int j = k >> 1; j; j >>= 1) {
        const unsigned pk = (unsigned)__shfl_xor((int)sk, j, 64);
        const float pe = __shfl_xor(se, j, 64);
        const bool takeMin = (((lane & j) == 0) == ((lane & k) == 0));
        const bool sw = takeMin ? (pk < sk) : (pk > sk);
        if (sw) {
          sk = pk;
          se = pe;
        }
      }
    }

    float pre = se;
#pragma unroll
    for (int off = 1; off <= 32; off <<= 1) {
      const float t = __shfl_up(pre, off, 64);
      if (lane >= off) pre += t;
    }
    const float excl = pre - se;
    const bool keep = (excl <= limit);
    const unsigned long long km = __ballot(keep);
    const int L = 63 - __builtin_clzll(km);
    const unsigned thr = ~(unsigned)__shfl((int)sk, L, 64);

    float z2l = 0.f;
#pragma unroll
    for (int j = 0; j < 16; ++j) z2l += (u[qq][j] >= thr) ? e[j] : 0.f;
    const float Z2 = wsumf(z2l);
    const float wsc = fac[(b << 10) + q0 + qq] / Z2;

    int M = 0;
#pragma unroll
    for (int j = 0; j < 16; ++j) {
      const bool f = (u[qq][j] >= thr);
      const unsigned long long mb = __ballot(f);
      if (f) {
        const int pos = M + (int)__popcll(mb & ltmask);
        if (pos < 64) {
          ck[wid][pos] = ((j >> 2) << 8) + (lane << 2) + (j & 3);
          cv[wid][pos] = e[j] * wsc;
        }
      }
      M += (int)__popcll(mb);
    }
    if (M > 64) M = 64;

    float a0 = 0.f, a1 = 0.f, a2 = 0.f, a3 = 0.f;
    int i = 0;
    for (; i + 4 <= M; i += 4) {
      const int k0 = ck[wid][i], k1 = ck[wid][i + 1];
      const int k2 = ck[wid][i + 2], k3 = ck[wid][i + 3];
      const float c0 = cv[wid][i], c1 = cv[wid][i + 1];
      const float c2 = cv[wid][i + 2], c3 = cv[wid][i + 3];
      a0 = fmaf(c0, vb[((size_t)k0 << 6) + lane], a0);
      a1 = fmaf(c1, vb[((size_t)k1 << 6) + lane], a1);
      a2 = fmaf(c2, vb[((size_t)k2 << 6) + lane], a2);
      a3 = fmaf(c3, vb[((size_t)k3 << 6) + lane], a3);
    }
    for (; i < M; ++i)
      a0 = fmaf(cv[wid][i], vb[((size_t)ck[wid][i] << 6) + lane], a0);
    const float o = (a0 + a1) + (a2 + a3);

    // store as 2-term bf16 planes for the MFMA out-projection
    const unsigned pk2 = splitf2(o);
    const size_t idx = (((size_t)b << 10) + q0 + qq) * C_ + (h << 6) + lane;
    aoh[idx] = (ushort_t)(pk2 & 0xffffu);
    aom[idx] = (ushort_t)(pk2 >> 16);
  }
}

extern "C" void kernel_launch(void* const* d_in, const int* in_sizes, int n_in,
                              void* d_out, int out_size, void* d_ws,
                              size_t ws_size, hipStream_t stream) {
  const float* x = (const float*)d_in[0];
  const float* wqkv = (const float*)d_in[1];
  const float* wout = (const float*)d_in[2];
  const float* bout = (const float*)d_in[3];
  const float* alpha = (const float*)d_in[4];
  const float* beta = (const float*)d_in[5];
  float* out = (float*)d_out;

  float* ws = (float*)d_ws;
  const size_t M1 = 1u << 20;  // 1M floats
  float* qw = ws;              // 2M fl
  float* kt = ws + 2 * M1;     // 2M fl  [bh][d][n]
  float* vw = ws + 4 * M1;     // 2M fl
  float* fc = ws + 6 * M1;     // 2K fl (padded to 4K)
  float* base = ws + 6 * M1 + 4096;
  ushort_t* xh = (ushort_t*)(base);            // 2M ushorts (1M fl)
  ushort_t* xm = (ushort_t*)(base + 1 * M1);
  ushort_t* xl = (ushort_t*)(base + 2 * M1);
  ushort_t* wqh = (ushort_t*)(base + 3 * M1);  // 3M ushorts (1.5M fl)
  ushort_t* wqm = (ushort_t*)(base + 4 * M1 + M1 / 2);
  ushort_t* wql = (ushort_t*)(base + 6 * M1);
  // aliases (stream order makes these safe):
  ushort_t* woh = wql;            // w_out planes overwrite wql (dead after qk)
  ushort_t* wom = wql + 1 * M1;   // 1M ushorts each
  ushort_t* aoh = xh;             // attn planes overwrite x planes
  ushort_t* aom = xm;             // (dead after gemm_v)

  split3_kernel<<<2048, 256, 0, stream>>>(x, xh, xm, xl);
  split3_kernel<<<3072, 256, 0, stream>>>(wqkv, wqh, wqm, wql);
  factor_kernel<<<B_ * N_, 64, 0, stream>>>(x, alpha, beta, fc);
  gemm_qk_kernel<<<dim3(32, 16), 256, 0, stream>>>(xh, xm, xl, wqh, wqm, wql,
                                                   qw, kt);
  gemm_v_kernel<<<dim3(16, 16), 256, 0, stream>>>(xh, xm, wqh, wqm, vw);
  split2_kernel<<<1024, 256, 0, stream>>>(wout, woh, wom);
  attn_kernel<<<(B_ * H_ * N_) / 16, 256, 0, stream>>>(qw, kt, vw, fc, aoh,
                                                       aom);
  gemm_out_kernel<<<dim3(16, 16), 256, 0, stream>>>(aoh, aom, woh, wom, bout,
                                                    out);
}

// Round 14
// 377.255 us; speedup vs baseline: 1.1394x; 1.1394x over previous
//
#include <hip/hip_runtime.h>

#define B_ 2
#define N_ 1024
#define C_ 1024
#define H_ 16
#define HD_ 64
#define KPAD 36   // u32 per LDS row (144B stride): 16B-aligned b128 reads
#define KPADL 40  // u16 per LDS row (80B stride): 16B-aligned b128 reads

typedef short short8 __attribute__((ext_vector_type(8)));
typedef float f32x4 __attribute__((ext_vector_type(4)));

union U16 {
  uint4 q;
  unsigned u[4];
  short8 s;
};

// ---------- wave-wide (64-lane) helpers ----------
__device__ __forceinline__ float wsumf(float x) {
#pragma unroll
  for (int off = 32; off; off >>= 1) x += __shfl_xor(x, off, 64);
  return x;
}
__device__ __forceinline__ unsigned orderu(float f) {
  unsigned b = __float_as_uint(f);
  return (b & 0x80000000u) ? ~b : (b | 0x80000000u);
}
__device__ __forceinline__ float iorderu(unsigned x) {
  unsigned b = (x & 0x80000000u) ? (x & 0x7FFFFFFFu) : ~x;
  return __uint_as_float(b);
}

// 2-term split f32 -> packed u32: hi bf16 low16, lo bf16 high16 (RTNE)
__device__ __forceinline__ unsigned splitf2(float f) {
  unsigned u = __float_as_uint(f);
  unsigned t = (u + 0x7fffu + ((u >> 16) & 1u)) & 0xffff0000u;
  float r = f - __uint_as_float(t);  // exact
  unsigned v = __float_as_uint(r);
  unsigned tv = v + 0x7fffu + ((v >> 16) & 1u);
  return (t >> 16) | (tv & 0xffff0000u);
}
// 3-term split: hm = hi|mid packed u32, lo = third bf16 term
__device__ __forceinline__ void splitf3(float f, unsigned& hm,
                                        unsigned short& lo) {
  unsigned u = __float_as_uint(f);
  unsigned t = (u + 0x7fffu + ((u >> 16) & 1u)) & 0xffff0000u;
  float r1 = f - __uint_as_float(t);  // exact
  unsigned v = __float_as_uint(r1);
  unsigned tv = (v + 0x7fffu + ((v >> 16) & 1u)) & 0xffff0000u;
  float r2 = r1 - __uint_as_float(tv);  // exact
  unsigned w = __float_as_uint(r2);
  unsigned tw = w + 0x7fffu + ((w >> 16) & 1u);
  hm = (t >> 16) | tv;
  lo = (unsigned short)(tw >> 16);
}

__device__ __forceinline__ void unpack_hm(const unsigned* p, short8& h,
                                          short8& l) {
  const uint4 X = *(const uint4*)p;
  const uint4 Y = *(const uint4*)(p + 4);
  U16 Hh, Ll;
  Hh.u[0] = (X.x & 0xffffu) | (X.y << 16);
  Hh.u[1] = (X.z & 0xffffu) | (X.w << 16);
  Hh.u[2] = (Y.x & 0xffffu) | (Y.y << 16);
  Hh.u[3] = (Y.z & 0xffffu) | (Y.w << 16);
  Ll.u[0] = (X.x >> 16) | (X.y & 0xffff0000u);
  Ll.u[1] = (X.z >> 16) | (X.w & 0xffff0000u);
  Ll.u[2] = (Y.x >> 16) | (Y.y & 0xffff0000u);
  Ll.u[3] = (Y.z >> 16) | (Y.w & 0xffff0000u);
  h = Hh.s;
  l = Ll.s;
}

// ---------- 3-term split MFMA core, 128x64 tile, BK=32, 4 waves (2x2) ----------
// 6 products {h*l, l*h, m*m, h*m, m*h, h*h}, smallest-first (q/k precision).
__device__ __forceinline__ void mfma_core6(
    const float* __restrict__ A, const float* __restrict__ Bm, int lda,
    int ldb, int m0, int n0, unsigned* a_hm, unsigned* b_hm,
    unsigned short* a_lo, unsigned short* b_lo, f32x4 acc[4][2]) {
  const int tid = threadIdx.x;
  const int lane = tid & 63;
  const int wro = ((tid >> 7) & 1) * 64;  // wave row offset (0/64)
  const int wco = ((tid >> 6) & 1) * 32;  // wave col offset (0/32)
  const int a_k4 = (tid & 7) * 4, a_m = tid >> 3;  // A rows a_m+32j
  const int b_k = tid >> 4;                        // B k-rows b_k, b_k+16
  const int b_j4 = (tid & 15) * 4;                 // B col chunk
  const int fr = lane & 15, fk = (lane >> 4) * 8;

  float4 aR[4], bR[2];
#pragma unroll
  for (int j = 0; j < 4; ++j)
    aR[j] = *(const float4*)(A + (size_t)(m0 + a_m + 32 * j) * lda + a_k4);
  bR[0] = *(const float4*)(Bm + (size_t)b_k * ldb + n0 + b_j4);
  bR[1] = *(const float4*)(Bm + (size_t)(b_k + 16) * ldb + n0 + b_j4);

  for (int kt = 0; kt < 32; ++kt) {
    __syncthreads();  // prior iteration's frag reads done
#pragma unroll
    for (int j = 0; j < 4; ++j) {
      uint4 w;
      ushort4 l;
      splitf3(aR[j].x, w.x, l.x);
      splitf3(aR[j].y, w.y, l.y);
      splitf3(aR[j].z, w.z, l.z);
      splitf3(aR[j].w, w.w, l.w);
      *(uint4*)(a_hm + (a_m + 32 * j) * KPAD + a_k4) = w;
      *(ushort4*)(a_lo + (a_m + 32 * j) * KPADL + a_k4) = l;
    }
    {
      unsigned hm;
      unsigned short lo;
      splitf3(bR[0].x, hm, lo);
      b_hm[(b_j4 + 0) * KPAD + b_k] = hm;
      b_lo[(b_j4 + 0) * KPADL + b_k] = lo;
      splitf3(bR[0].y, hm, lo);
      b_hm[(b_j4 + 1) * KPAD + b_k] = hm;
      b_lo[(b_j4 + 1) * KPADL + b_k] = lo;
      splitf3(bR[0].z, hm, lo);
      b_hm[(b_j4 + 2) * KPAD + b_k] = hm;
      b_lo[(b_j4 + 2) * KPADL + b_k] = lo;
      splitf3(bR[0].w, hm, lo);
      b_hm[(b_j4 + 3) * KPAD + b_k] = hm;
      b_lo[(b_j4 + 3) * KPADL + b_k] = lo;
      splitf3(bR[1].x, hm, lo);
      b_hm[(b_j4 + 0) * KPAD + b_k + 16] = hm;
      b_lo[(b_j4 + 0) * KPADL + b_k + 16] = lo;
      splitf3(bR[1].y, hm, lo);
      b_hm[(b_j4 + 1) * KPAD + b_k + 16] = hm;
      b_lo[(b_j4 + 1) * KPADL + b_k + 16] = lo;
      splitf3(bR[1].z, hm, lo);
      b_hm[(b_j4 + 2) * KPAD + b_k + 16] = hm;
      b_lo[(b_j4 + 2) * KPADL + b_k + 16] = lo;
      splitf3(bR[1].w, hm, lo);
      b_hm[(b_j4 + 3) * KPAD + b_k + 16] = hm;
      b_lo[(b_j4 + 3) * KPADL + b_k + 16] = lo;
    }
    __syncthreads();
    if (kt + 1 < 32) {  // prefetch next k-tile; hides under MFMA
      const int kb = (kt + 1) * 32;
#pragma unroll
      for (int j = 0; j < 4; ++j)
        aR[j] =
            *(const float4*)(A + (size_t)(m0 + a_m + 32 * j) * lda + kb + a_k4);
      bR[0] = *(const float4*)(Bm + (size_t)(kb + b_k) * ldb + n0 + b_j4);
      bR[1] = *(const float4*)(Bm + (size_t)(kb + b_k + 16) * ldb + n0 + b_j4);
    }
    short8 ah[4], am[4], al[4];
#pragma unroll
    for (int rt = 0; rt < 4; ++rt) {
      const int row = wro + rt * 16 + fr;
      unpack_hm(a_hm + row * KPAD + fk, ah[rt], am[rt]);
      U16 L;
      L.q = *(const uint4*)(a_lo + row * KPADL + fk);
      al[rt] = L.s;
    }
#pragma unroll
    for (int ct = 0; ct < 2; ++ct) {
      const int row = wco + ct * 16 + fr;
      short8 bh, bm, bl;
      unpack_hm(b_hm + row * KPAD + fk, bh, bm);
      U16 L;
      L.q = *(const uint4*)(b_lo + row * KPADL + fk);
      bl = L.s;
#pragma unroll
      for (int rt = 0; rt < 4; ++rt) {
        f32x4 c = acc[rt][ct];
        c = __builtin_amdgcn_mfma_f32_16x16x32_bf16(ah[rt], bl, c, 0, 0, 0);
        c = __builtin_amdgcn_mfma_f32_16x16x32_bf16(al[rt], bh, c, 0, 0, 0);
        c = __builtin_amdgcn_mfma_f32_16x16x32_bf16(am[rt], bm, c, 0, 0, 0);
        c = __builtin_amdgcn_mfma_f32_16x16x32_bf16(ah[rt], bm, c, 0, 0, 0);
        c = __builtin_amdgcn_mfma_f32_16x16x32_bf16(am[rt], bh, c, 0, 0, 0);
        c = __builtin_amdgcn_mfma_f32_16x16x32_bf16(ah[rt], bh, c, 0, 0, 0);
        acc[rt][ct] = c;
      }
    }
  }
}

// ---------- 2-term split MFMA core, 128x64 tile (v / out-proj) ----------
// 3 products {h*l, l*h, h*h}, smallest-first.
__device__ __forceinline__ void mfma_core3(const float* __restrict__ A,
                                           const float* __restrict__ Bm,
                                           int lda, int ldb, int m0, int n0,
                                           unsigned* a_hm, unsigned* b_hm,
                                           f32x4 acc[4][2]) {
  const int tid = threadIdx.x;
  const int lane = tid & 63;
  const int wro = ((tid >> 7) & 1) * 64;
  const int wco = ((tid >> 6) & 1) * 32;
  const int a_k4 = (tid & 7) * 4, a_m = tid >> 3;
  const int b_k = tid >> 4;
  const int b_j4 = (tid & 15) * 4;
  const int fr = lane & 15, fk = (lane >> 4) * 8;

  float4 aR[4], bR[2];
#pragma unroll
  for (int j = 0; j < 4; ++j)
    aR[j] = *(const float4*)(A + (size_t)(m0 + a_m + 32 * j) * lda + a_k4);
  bR[0] = *(const float4*)(Bm + (size_t)b_k * ldb + n0 + b_j4);
  bR[1] = *(const float4*)(Bm + (size_t)(b_k + 16) * ldb + n0 + b_j4);

  for (int kt = 0; kt < 32; ++kt) {
    __syncthreads();
#pragma unroll
    for (int j = 0; j < 4; ++j) {
      uint4 w;
      w.x = splitf2(aR[j].x);
      w.y = splitf2(aR[j].y);
      w.z = splitf2(aR[j].z);
      w.w = splitf2(aR[j].w);
      *(uint4*)(a_hm + (a_m + 32 * j) * KPAD + a_k4) = w;
    }
    {
      b_hm[(b_j4 + 0) * KPAD + b_k] = splitf2(bR[0].x);
      b_hm[(b_j4 + 1) * KPAD + b_k] = splitf2(bR[0].y);
      b_hm[(b_j4 + 2) * KPAD + b_k] = splitf2(bR[0].z);
      b_hm[(b_j4 + 3) * KPAD + b_k] = splitf2(bR[0].w);
      b_hm[(b_j4 + 0) * KPAD + b_k + 16] = splitf2(bR[1].x);
      b_hm[(b_j4 + 1) * KPAD + b_k + 16] = splitf2(bR[1].y);
      b_hm[(b_j4 + 2) * KPAD + b_k + 16] = splitf2(bR[1].z);
      b_hm[(b_j4 + 3) * KPAD + b_k + 16] = splitf2(bR[1].w);
    }
    __syncthreads();
    if (kt + 1 < 32) {
      const int kb = (kt + 1) * 32;
#pragma unroll
      for (int j = 0; j < 4; ++j)
        aR[j] =
            *(const float4*)(A + (size_t)(m0 + a_m + 32 * j) * lda + kb + a_k4);
      bR[0] = *(const float4*)(Bm + (size_t)(kb + b_k) * ldb + n0 + b_j4);
      bR[1] = *(const float4*)(Bm + (size_t)(kb + b_k + 16) * ldb + n0 + b_j4);
    }
    short8 ah[4], al[4];
#pragma unroll
    for (int rt = 0; rt < 4; ++rt)
      unpack_hm(a_hm + (wro + rt * 16 + fr) * KPAD + fk, ah[rt], al[rt]);
#pragma unroll
    for (int ct = 0; ct < 2; ++ct) {
      short8 bh, bl;
      unpack_hm(b_hm + (wco + ct * 16 + fr) * KPAD + fk, bh, bl);
#pragma unroll
      for (int rt = 0; rt < 4; ++rt) {
        f32x4 c = acc[rt][ct];
        c = __builtin_amdgcn_mfma_f32_16x16x32_bf16(ah[rt], bl, c, 0, 0, 0);
        c = __builtin_amdgcn_mfma_f32_16x16x32_bf16(al[rt], bh, c, 0, 0, 0);
        c = __builtin_amdgcn_mfma_f32_16x16x32_bf16(ah[rt], bh, c, 0, 0, 0);
        acc[rt][ct] = c;
      }
    }
  }
}

// ---------- fused front: qk tiles (0..511) + v tiles (512..767) +
//            NKAT factor groups (768..1279), one dispatch ----------
__global__ __launch_bounds__(256) void front_kernel(
    const float* __restrict__ x, const float* __restrict__ w,
    const float* __restrict__ alpha_p, const float* __restrict__ beta_p,
    float* __restrict__ q, float* __restrict__ ktb, float* __restrict__ v,
    float* __restrict__ fac) {
  __shared__ unsigned a_hm[128 * KPAD];
  __shared__ unsigned b_hm[64 * KPAD];
  __shared__ unsigned short a_lo[128 * KPADL];
  __shared__ unsigned short b_lo[64 * KPADL];

  const int bid = blockIdx.x;
  const int lane = threadIdx.x & 63;

  if (bid < 512) {  // ---- qk tile (6-product, 3-term split) ----
    f32x4 acc[4][2];
#pragma unroll
    for (int i = 0; i < 4; ++i)
#pragma unroll
      for (int j = 0; j < 2; ++j) acc[i][j] = (f32x4){0.f, 0.f, 0.f, 0.f};
    const int m0 = (bid >> 5) * 128, n0 = (bid & 31) * 64;
    mfma_core6(x, w, C_, 3 * C_, m0, n0, a_hm, b_hm, a_lo, b_lo, acc);

    const int wro = ((threadIdx.x >> 7) & 1) * 64;
    const int wco = ((threadIdx.x >> 6) & 1) * 32;
    const int rbase = (lane >> 4) * 4, cc = lane & 15;
#pragma unroll
    for (int rt = 0; rt < 4; ++rt) {
      const int m = m0 + wro + rt * 16 + rbase;
      const int bb2 = m >> 10, nn = m & 1023;
#pragma unroll
      for (int ct = 0; ct < 2; ++ct) {
        const int j = n0 + wco + ct * 16 + cc;
        const int sel = j >> 10, hh = (j >> 6) & 15, d0 = j & 63;
        const f32x4 c = acc[rt][ct];
        if (sel == 1) {  // K transposed: contiguous along token index nn
          *(float4*)(ktb + (((size_t)(bb2 * 16 + hh) * HD_ + d0) << 10) + nn) =
              make_float4(c[0], c[1], c[2], c[3]);
        } else {
          float* dst = q + (((size_t)(bb2 * 16 + hh) << 10) + nn) * HD_ + d0;
          dst[0] = c[0];
          dst[HD_] = c[1];
          dst[2 * HD_] = c[2];
          dst[3 * HD_] = c[3];
        }
      }
    }
  } else if (bid < 768) {  // ---- v tile (3-product, 2-term split) ----
    f32x4 acc[4][2];
#pragma unroll
    for (int i = 0; i < 4; ++i)
#pragma unroll
      for (int j = 0; j < 2; ++j) acc[i][j] = (f32x4){0.f, 0.f, 0.f, 0.f};
    const int vb = bid - 512;
    const int m0 = (vb >> 4) * 128, n0 = 2048 + (vb & 15) * 64;
    mfma_core3(x, w, C_, 3 * C_, m0, n0, a_hm, b_hm, acc);

    const int wro = ((threadIdx.x >> 7) & 1) * 64;
    const int wco = ((threadIdx.x >> 6) & 1) * 32;
    const int rbase = (lane >> 4) * 4, cc = lane & 15;
#pragma unroll
    for (int rt = 0; rt < 4; ++rt) {
      const int m = m0 + wro + rt * 16 + rbase;
      const int bb = m >> 10, nn = m & 1023;
#pragma unroll
      for (int ct = 0; ct < 2; ++ct) {
        const int jv = (n0 - 2048) + wco + ct * 16 + cc;
        const int hh = (jv >> 6) & 15, d0 = jv & 63;
        const f32x4 c = acc[rt][ct];
        float* dst = v + (((size_t)(bb * 16 + hh) << 10) + nn) * HD_ + d0;
        dst[0] = c[0];
        dst[HD_] = c[1];
        dst[2 * HD_] = c[2];
        dst[3 * HD_] = c[3];
      }
    }
  } else {  // ---- NKAT factor: 4 rows per block (one per wave) ----
    const int row = (bid - 768) * 4 + (threadIdx.x >> 6);
    const float4* xr = (const float4*)(x + (size_t)row * C_);
    float s = 0.f, ss = 0.f;
#pragma unroll
    for (int j = 0; j < 4; ++j) {
      float4 vv = xr[lane + 64 * j];
      s += vv.x + vv.y + vv.z + vv.w;
      ss += vv.x * vv.x + vv.y * vv.y + vv.z * vv.z + vv.w * vv.w;
    }
    s = wsumf(s);
    ss = wsumf(ss);
    const float mean = s * (1.f / 1024.f);
    const float var = ss * (1.f / 1024.f) - mean * mean;
    const float theta =
        alpha_p[0] * tanhf(mean) + beta_p[0] * (1.f / (1.f + __expf(-var)));
    if (lane == 0) fac[row] = 1.f + 0.45125f * theta;  // lc = 0.5*0.95^2
  }
}

// ---------- out = attn_out @ w_out + b_out ----------
__global__ __launch_bounds__(256) void gemm_out_kernel(
    const float* __restrict__ a, const float* __restrict__ w,
    const float* __restrict__ bias, float* __restrict__ out) {
  __shared__ unsigned a_hm[128 * KPAD];
  __shared__ unsigned b_hm[64 * KPAD];
  f32x4 acc[4][2];
#pragma unroll
  for (int i = 0; i < 4; ++i)
#pragma unroll
    for (int j = 0; j < 2; ++j) acc[i][j] = (f32x4){0.f, 0.f, 0.f, 0.f};
  const int m0 = blockIdx.y * 128, n0 = blockIdx.x * 64;
  mfma_core3(a, w, C_, C_, m0, n0, a_hm, b_hm, acc);

  const int lane = threadIdx.x & 63;
  const int wro = ((threadIdx.x >> 7) & 1) * 64;
  const int wco = ((threadIdx.x >> 6) & 1) * 32;
  const int rbase = (lane >> 4) * 4, cc = lane & 15;
#pragma unroll
  for (int rt = 0; rt < 4; ++rt) {
    const int m = m0 + wro + rt * 16 + rbase;
#pragma unroll
    for (int ct = 0; ct < 2; ++ct) {
      const int j = n0 + wco + ct * 16 + cc;
      const float bj = bias[j];
      const f32x4 c = acc[rt][ct];
      float* dst = out + (size_t)m * C_ + j;
      dst[0] = c[0] + bj;
      dst[C_] = c[1] + bj;
      dst[2 * C_] = c[2] + bj;
      dst[3 * C_] = c[3] + bj;
    }
  }
}

// ---------- attention: round-12 kernel, unchanged (verified) ----------
__global__ __launch_bounds__(256) void attn_kernel(
    const float* __restrict__ qw, const float* __restrict__ kt,
    const float* __restrict__ vw, const float* __restrict__ fac,
    float* __restrict__ ao) {
  const int lane = threadIdx.x & 63;
  const int wid = threadIdx.x >> 6;
  const int qblk = blockIdx.x * 16;
  const int bh = qblk >> 10;
  const int b = bh >> 4, h = bh & 15;
  const int q0 = (qblk & (N_ - 1)) + wid * 4;

  __shared__ __align__(16) float q_ldsT[4][HD_][4];
  __shared__ unsigned su[4][64];
  __shared__ float sv[4][64];
  __shared__ int ck[4][64];
  __shared__ float cv[4][64];

  {
    const int qq = lane >> 4, dp = (lane & 15) << 2;
    const float4 v =
        *(const float4*)(qw + ((size_t)bh * N_ + q0 + qq) * HD_ + dp);
    q_ldsT[wid][dp + 0][qq] = v.x;
    q_ldsT[wid][dp + 1][qq] = v.y;
    q_ldsT[wid][dp + 2][qq] = v.z;
    q_ldsT[wid][dp + 3][qq] = v.w;
  }

  const float* ktb = kt + ((size_t)bh * HD_ * N_);
  const unsigned long long ltmask = (1ull << lane) - 1ull;
  unsigned u[4][16];

  for (int pass = 0; pass < 4; ++pass) {
    float acc[4][4];
#pragma unroll
    for (int a = 0; a < 4; ++a)
#pragma unroll
      for (int c = 0; c < 4; ++c) acc[a][c] = 0.f;
    const float* kp = ktb + (pass << 8) + (lane << 2);
#pragma unroll 4
    for (int d = 0; d < HD_; ++d) {
      const float4 kv = *(const float4*)(kp + (size_t)d * N_);
      const float4 qv = *(const float4*)(&q_ldsT[wid][d][0]);
      acc[0][0] = fmaf(kv.x, qv.x, acc[0][0]);
      acc[0][1] = fmaf(kv.x, qv.y, acc[0][1]);
      acc[0][2] = fmaf(kv.x, qv.z, acc[0][2]);
      acc[0][3] = fmaf(kv.x, qv.w, acc[0][3]);
      acc[1][0] = fmaf(kv.y, qv.x, acc[1][0]);
      acc[1][1] = fmaf(kv.y, qv.y, acc[1][1]);
      acc[1][2] = fmaf(kv.y, qv.z, acc[1][2]);
      acc[1][3] = fmaf(kv.y, qv.w, acc[1][3]);
      acc[2][0] = fmaf(kv.z, qv.x, acc[2][0]);
      acc[2][1] = fmaf(kv.z, qv.y, acc[2][1]);
      acc[2][2] = fmaf(kv.z, qv.z, acc[2][2]);
      acc[2][3] = fmaf(kv.z, qv.w, acc[2][3]);
      acc[3][0] = fmaf(kv.w, qv.x, acc[3][0]);
      acc[3][1] = fmaf(kv.w, qv.y, acc[3][1]);
      acc[3][2] = fmaf(kv.w, qv.z, acc[3][2]);
      acc[3][3] = fmaf(kv.w, qv.w, acc[3][3]);
    }
#pragma unroll
    for (int jl = 0; jl < 4; ++jl)
#pragma unroll
      for (int q = 0; q < 4; ++q)
        u[q][(pass << 2) + jl] = orderu((acc[jl][q] * 0.125f) / 0.8f);
  }

  unsigned mu[4], l0[4];
#pragma unroll
  for (int q = 0; q < 4; ++q) {
    unsigned mq = u[q][0];
#pragma unroll
    for (int j = 1; j < 16; ++j) mq = max(mq, u[q][j]);
    mu[q] = mq;
    l0[q] = mq;
  }
#pragma unroll
  for (int off = 32; off; off >>= 1) {
#pragma unroll
    for (int q = 0; q < 4; ++q) {
      mu[q] = max(mu[q], (unsigned)__shfl_xor((int)mu[q], off, 64));
      l0[q] = min(l0[q], (unsigned)__shfl_xor((int)l0[q], off, 64));
    }
  }

  unsigned lo[4], hi[4];
#pragma unroll
  for (int q = 0; q < 4; ++q) {
    lo[q] = l0[q];
    hi[q] = mu[q];
  }
  while ((lo[0] < hi[0]) | (lo[1] < hi[1]) | (lo[2] < hi[2]) |
         (lo[3] < hi[3])) {
#pragma unroll
    for (int q = 0; q < 4; ++q) {
      if (lo[q] < hi[q]) {
        const unsigned mid = lo[q] + ((hi[q] - lo[q]) >> 1) + 1u;
        int c = 0;
#pragma unroll
        for (int j = 0; j < 16; ++j)
          c += (int)__popcll(__ballot(u[q][j] >= mid));
        if (c >= 64) lo[q] = mid;
        else hi[q] = mid - 1u;
      }
    }
  }

  const float* vb = vw + ((size_t)bh << 16);
#pragma unroll
  for (int qq = 0; qq < 4; ++qq) {
    const unsigned kthu = lo[qq];
    const float m = iorderu(mu[qq]);

    float e[16];
    float zl = 0.f;
#pragma unroll
    for (int j = 0; j < 16; ++j) {
      const float ej = (u[qq][j] >= kthu) ? __expf(iorderu(u[qq][j]) - m) : 0.f;
      e[j] = ej;
      zl += ej;
    }
    const float Z = wsumf(zl);
    const float limit = 0.9f * Z;

    int base = 0;
#pragma unroll
    for (int j = 0; j < 16; ++j) {
      const bool f = (u[qq][j] >= kthu);
      const unsigned long long mb = __ballot(f);
      if (f) {
        const int pos = base + (int)__popcll(mb & ltmask);
        if (pos < 64) {
          su[wid][pos] = u[qq][j];
          sv[wid][pos] = e[j];
        }
      }
      base += (int)__popcll(mb);
    }

    unsigned sk = ~su[wid][lane];
    float se = sv[wid][lane];
#pragma unroll
    for (int k = 2; k <= 64; k <<= 1) {
#pragma unroll
      for (int j = k >> 1; j; j >>= 1) {
        const unsigned pk = (unsigned)__shfl_xor((int)sk, j, 64);
        const float pe = __shfl_xor(se, j, 64);
        const bool takeMin = (((lane & j) == 0) == ((lane & k) == 0));
        const bool sw = takeMin ? (pk < sk) : (pk > sk);
        if (sw) {
          sk = pk;
          se = pe;
        }
      }
    }

    float pre = se;
#pragma unroll
    for (int off = 1; off <= 32; off <<= 1) {
      const float t = __shfl_up(pre, off, 64);
      if (lane >= off) pre += t;
    }
    const float excl = pre - se;
    const bool keep = (excl <= limit);
    const unsigned long long km = __ballot(keep);
    const int L = 63 - __builtin_clzll(km);
    const unsigned thr = ~(unsigned)__shfl((int)sk, L, 64);

    float z2l = 0.f;
#pragma unroll
    for (int j = 0; j < 16; ++j) z2l += (u[qq][j] >= thr) ? e[j] : 0.f;
    const float Z2 = wsumf(z2l);
    const float wsc = fac[(b << 10) + q0 + qq] / Z2;

    int M = 0;
#pragma unroll
    for (int j = 0; j < 16; ++j) {
      const bool f = (u[qq][j] >= thr);
      const unsigned long long mb = __ballot(f);
      if (f) {
        const int pos = M + (int)__popcll(mb & ltmask);
        if (pos < 64) {
          ck[wid][pos] = ((j >> 2) << 8) + (lane << 2) + (j & 3);
          cv[wid][pos] = e[j] * wsc;
        }
      }
      M += (int)__popcll(mb);
    }
    if (M > 64) M = 64;

    float a0 = 0.f, a1 = 0.f, a2 = 0.f, a3 = 0.f;
    int i = 0;
    for (; i + 4 <= M; i += 4) {
      const int k0 = ck[wid][i], k1 = ck[wid][i + 1];
      const int k2 = ck[wid][i + 2], k3 = ck[wid][i + 3];
      const float c0 = cv[wid][i], c1 = cv[wid][i + 1];
      const float c2 = cv[wid][i + 2], c3 = cv[wid][i + 3];
      a0 = fmaf(c0, vb[((size_t)k0 << 6) + lane], a0);
      a1 = fmaf(c1, vb[((size_t)k1 << 6) + lane], a1);
      a2 = fmaf(c2, vb[((size_t)k2 << 6) + lane], a2);
      a3 = fmaf(c3, vb[((size_t)k3 << 6) + lane], a3);
    }
    for (; i < M; ++i)
      a0 = fmaf(cv[wid][i], vb[((size_t)ck[wid][i] << 6) + lane], a0);
    const float o = (a0 + a1) + (a2 + a3);

    ao[(((size_t)b << 10) + q0 + qq) * C_ + (h << 6) + lane] = o;
  }
}

extern "C" void kernel_launch(void* const* d_in, const int* in_sizes, int n_in,
                              void* d_out, int out_size, void* d_ws,
                              size_t ws_size, hipStream_t stream) {
  const float* x = (const float*)d_in[0];
  const float* wqkv = (const float*)d_in[1];
  const float* wout = (const float*)d_in[2];
  const float* bout = (const float*)d_in[3];
  const float* alpha = (const float*)d_in[4];
  const float* beta = (const float*)d_in[5];
  float* out = (float*)d_out;

  float* ws = (float*)d_ws;
  const size_t SZ = (size_t)B_ * H_ * N_ * HD_;  // 2M floats
  float* qw = ws;
  float* kt = ws + SZ;  // K transposed per head: [bh][d][n]
  float* vw = ws + 2 * SZ;
  float* ao = ws + 3 * SZ;
  float* fc = ws + 4 * SZ;

  front_kernel<<<1280, 256, 0, stream>>>(x, wqkv, alpha, beta, qw, kt, vw, fc);
  attn_kernel<<<(B_ * H_ * N_) / 16, 256, 0, stream>>>(qw, kt, vw, fc, ao);
  gemm_out_kernel<<<dim3(16, 16), 256, 0, stream>>>(ao, wout, bout, out);
}